// Round 4
// baseline (305.342 us; speedup 1.0000x reference)
//
#include <hip/hip_runtime.h>
#include <hip/hip_bf16.h>
#include <stdint.h>

#define M_DIM 8192
#define N_DIM 4096   // OUT_F
#define K_DIM 4096   // IN_F

#define BM 256
#define BN 256
#define BK 32
#define NT (K_DIM / BK)   // 128 K-tiles
#define NBUF 4

typedef __bf16 bf16_t;
typedef __attribute__((ext_vector_type(8))) __bf16 bf16x8;
typedef __attribute__((ext_vector_type(16))) float f32x16;

// ---------------- fp32 -> bf16 convert (vectorized, grid-stride) ----------------
__global__ void cvt_f32_to_bf16(const float* __restrict__ in, bf16_t* __restrict__ out, int n8) {
    int stride = gridDim.x * blockDim.x;
    for (int i = blockIdx.x * blockDim.x + threadIdx.x; i < n8; i += stride) {
        const float4* p = reinterpret_cast<const float4*>(in) + 2 * (size_t)i;
        float4 v0 = p[0];
        float4 v1 = p[1];
        bf16x8 o;
        o[0] = (bf16_t)v0.x; o[1] = (bf16_t)v0.y; o[2] = (bf16_t)v0.z; o[3] = (bf16_t)v0.w;
        o[4] = (bf16_t)v1.x; o[5] = (bf16_t)v1.y; o[6] = (bf16_t)v1.z; o[7] = (bf16_t)v1.w;
        *(reinterpret_cast<bf16x8*>(out) + (size_t)i) = o;
    }
}

// ---------------- 256x256 bf16 GEMM, 32x32x16 MFMA, group-interleaved ----------------
// A: [M][K] bf16 row-major; B: [N][K] bf16 row-major (weight = B^T layout);
// C = A*B^T + bias, fp32 out.
//
// 4-deep LDS K-tile ring (BK=32). Per tile: 8 groups of {ds_read for a LATER
// group | 2 MFMA}; tile-entry operands (4 B-frags + a[0][0]) were read during
// the PREVIOUS tile's back half ("read-ahead"), after the mid-tile
// vmcnt(8)+barrier published the next tile's staged data. B-frags double-
// buffered in registers via 2-tile unroll. Two barriers/tile:
//   MID (after vmcnt(8)): publishes tile t+1 for read-ahead (RAW on stage).
//   END: separates tile t-1's in-flight reads from STAGE(t+3)'s DMA
//        overwrite of buf[(t-1)&3] (WAR). All reads are register-consumed
//        (compiler lgkmcnt before MFMA/next use) before the barrier they
//        depend on.

#define MF32(a, b, c) __builtin_amdgcn_mfma_f32_32x32x16_bf16((a), (b), (c), 0, 0, 0)
#define LD8(p) (*reinterpret_cast<const bf16x8*>(p))

#define STAGE_A(T) {                                                                  \
    const int sb_ = (T) & 3; const size_t kof_ = (size_t)(T) * BK;                    \
    __builtin_amdgcn_global_load_lds(                                                 \
        (const __attribute__((address_space(1))) void*)(gA0 + kof_),                  \
        (__attribute__((address_space(3))) void*)(&smem[sb_][0][dst0]), 16, 0, 0);    \
    __builtin_amdgcn_global_load_lds(                                                 \
        (const __attribute__((address_space(1))) void*)(gA1 + kof_),                  \
        (__attribute__((address_space(3))) void*)(&smem[sb_][0][dst1]), 16, 0, 0);    \
}

#define STAGE_B(T) {                                                                  \
    const int sb_ = (T) & 3; const size_t kof_ = (size_t)(T) * BK;                    \
    __builtin_amdgcn_global_load_lds(                                                 \
        (const __attribute__((address_space(1))) void*)(gB0 + kof_),                  \
        (__attribute__((address_space(3))) void*)(&smem[sb_][1][dst0]), 16, 0, 0);    \
    __builtin_amdgcn_global_load_lds(                                                 \
        (const __attribute__((address_space(1))) void*)(gB1 + kof_),                  \
        (__attribute__((address_space(3))) void*)(&smem[sb_][1][dst1]), 16, 0, 0);    \
}

// Groups (per wave): g_i computes acc[i][0..1] for kstep 0 (i=0..3), then
// kstep 1 (g4..g7). Reads are ≥1 group ahead of first use. Read-ahead (RA)
// of tile T+1's B-frags + a00 happens in g4..g7, after MID barrier.
#define TILE32(T, BC0, BC1, BC2, BC3, BN0, BN1, BN2, BN3, AC0, AN0, STG, VMSTR, RA)   \
do {                                                                                  \
    bf16_t* Al_ = &smem[(T) & 3][0][0];                                               \
    bf16_t* Bn_ = &smem[((T) + 1) & 3][1][0];                                         \
    bf16_t* An_ = &smem[((T) + 1) & 3][0][0];                                         \
    if (STG) STAGE_A((T) + 3);                                                        \
    bf16x8 a10_ = LD8(Al_ + oa10), a20_ = LD8(Al_ + oa20);                            \
    __builtin_amdgcn_s_setprio(1);                                                    \
    acc[0][0] = MF32(AC0, BC0, acc[0][0]); acc[0][1] = MF32(AC0, BC1, acc[0][1]);     \
    __builtin_amdgcn_s_setprio(0);                                                    \
    bf16x8 a30_ = LD8(Al_ + oa30), a01_ = LD8(Al_ + oa01);                            \
    __builtin_amdgcn_s_setprio(1);                                                    \
    acc[1][0] = MF32(a10_, BC0, acc[1][0]); acc[1][1] = MF32(a10_, BC1, acc[1][1]);   \
    __builtin_amdgcn_s_setprio(0);                                                    \
    if (STG) STAGE_B((T) + 3);                                                        \
    bf16x8 a11_ = LD8(Al_ + oa11);                                                    \
    __builtin_amdgcn_s_setprio(1);                                                    \
    acc[2][0] = MF32(a20_, BC0, acc[2][0]); acc[2][1] = MF32(a20_, BC1, acc[2][1]);   \
    __builtin_amdgcn_s_setprio(0);                                                    \
    bf16x8 a21_ = LD8(Al_ + oa21);                                                    \
    __builtin_amdgcn_s_setprio(1);                                                    \
    acc[3][0] = MF32(a30_, BC0, acc[3][0]); acc[3][1] = MF32(a30_, BC1, acc[3][1]);   \
    __builtin_amdgcn_s_setprio(0);                                                    \
    asm volatile(VMSTR ::: "memory");                                                 \
    __builtin_amdgcn_s_barrier();   /* MID: tile T+1 staged data now visible */       \
    bf16x8 a31_ = LD8(Al_ + oa31);                                                    \
    if (RA) { BN0 = LD8(Bn_ + ob00); }                                                \
    __builtin_amdgcn_s_setprio(1);                                                    \
    acc[0][0] = MF32(a01_, BC2, acc[0][0]); acc[0][1] = MF32(a01_, BC3, acc[0][1]);   \
    __builtin_amdgcn_s_setprio(0);                                                    \
    if (RA) { BN1 = LD8(Bn_ + ob10); BN2 = LD8(Bn_ + ob01); }                         \
    __builtin_amdgcn_s_setprio(1);                                                    \
    acc[1][0] = MF32(a11_, BC2, acc[1][0]); acc[1][1] = MF32(a11_, BC3, acc[1][1]);   \
    __builtin_amdgcn_s_setprio(0);                                                    \
    if (RA) { BN3 = LD8(Bn_ + ob11); }                                                \
    __builtin_amdgcn_s_setprio(1);                                                    \
    acc[2][0] = MF32(a21_, BC2, acc[2][0]); acc[2][1] = MF32(a21_, BC3, acc[2][1]);   \
    __builtin_amdgcn_s_setprio(0);                                                    \
    if (RA) { AN0 = LD8(An_ + oa00); }                                                \
    __builtin_amdgcn_s_setprio(1);                                                    \
    acc[3][0] = MF32(a31_, BC2, acc[3][0]); acc[3][1] = MF32(a31_, BC3, acc[3][1]);   \
    __builtin_amdgcn_s_setprio(0);                                                    \
    __builtin_amdgcn_s_barrier();   /* END: WAR fence for next STAGE */               \
} while (0)

__global__ __launch_bounds__(512, 2) void gemm_bf16_32x32(
        const bf16_t* __restrict__ A, const bf16_t* __restrict__ B,
        const float* __restrict__ bias, float* __restrict__ C) {

    __shared__ __align__(16) bf16_t smem[NBUF][2][BM * BK];   // 4 x (A,B) x 16KB = 128 KiB

    const int tid  = threadIdx.x;
    const int lane = tid & 63;
    const int wave = tid >> 6;        // 0..7
    const int wm   = wave >> 2;       // 0..1 : M half (128 rows)
    const int wn   = wave & 3;        // 0..3 : N quarter (64 cols)

    // XCD-aware swizzle (nwg = 512, divisible by 8 -> bijective)
    const int nwg = gridDim.x;
    const int cpx = nwg >> 3;
    const int swz = (blockIdx.x & 7) * cpx + (blockIdx.x >> 3);
    const int ntn = N_DIM / BN;       // 16
    const int brow = (swz / ntn) * BM;
    const int bcol = (swz % ntn) * BN;

    // ---- staging geometry (unchanged from r2/r3): tile = 256 rows x 32 bf16 =
    // 16KB = 1024 x 16B chunks; slot s holds (row = s>>2, chunk = (s&3)^((s>>3)&3)).
    const int slot0 = wave * 128 + lane;
    const int slot1 = slot0 + 64;
    const int r0 = slot0 >> 2, c0 = ((slot0 & 3) ^ ((slot0 >> 3) & 3)) << 3;
    const int r1 = slot1 >> 2, c1 = ((slot1 & 3) ^ ((slot1 >> 3) & 3)) << 3;
    const bf16_t* gA0 = A + (size_t)(brow + r0) * K_DIM + c0;
    const bf16_t* gA1 = A + (size_t)(brow + r1) * K_DIM + c1;
    const bf16_t* gB0 = B + (size_t)(bcol + r0) * K_DIM + c0;
    const bf16_t* gB1 = B + (size_t)(bcol + r1) * K_DIM + c1;
    const int dst0 = wave * 1024;     // elem offset (slot * 8)
    const int dst1 = dst0 + 512;

    // ---- ds_read fragment offsets (elems) for 32x32x16 frags, swizzle-matched.
    // A-frag (m-tile i, kstep s): row = wm*128+i*32+(lane&31), k-chunk = s*2+(lane>>5)
    // B-frag (n-tile j, kstep s): row = wn*64 +j*32+(lane&31), same chunk
    const int fr32 = lane & 31;
    const int kc   = lane >> 5;       // 0..1
#define AOFF32(i, s) ({ int row_ = wm*128 + (i)*32 + fr32; int cc_ = (s)*2 + kc;      \
                        row_*32 + ((cc_ ^ ((row_ >> 1) & 3)) << 3); })
#define BOFF32(j, s) ({ int row_ = wn*64 + (j)*32 + fr32; int cc_ = (s)*2 + kc;       \
                        row_*32 + ((cc_ ^ ((row_ >> 1) & 3)) << 3); })
    const int oa00 = AOFF32(0,0), oa10 = AOFF32(1,0), oa20 = AOFF32(2,0), oa30 = AOFF32(3,0);
    const int oa01 = AOFF32(0,1), oa11 = AOFF32(1,1), oa21 = AOFF32(2,1), oa31 = AOFF32(3,1);
    const int ob00 = BOFF32(0,0), ob10 = BOFF32(1,0), ob01 = BOFF32(0,1), ob11 = BOFF32(1,1);

    f32x16 acc[4][2];
#pragma unroll
    for (int i = 0; i < 4; i++)
#pragma unroll
        for (int j = 0; j < 2; j++)
#pragma unroll
            for (int r = 0; r < 16; r++) acc[i][j][r] = 0.f;

    // ---- prologue: stage tiles 0,1,2; land tile 0; read tile-0 entry frags
    STAGE_A(0) STAGE_B(0)
    STAGE_A(1) STAGE_B(1)
    STAGE_A(2) STAGE_B(2)
    asm volatile("s_waitcnt vmcnt(8)" ::: "memory");
    __builtin_amdgcn_s_barrier();

    bf16x8 bcE0 = LD8(&smem[0][1][0] + ob00);
    bf16x8 bcE1 = LD8(&smem[0][1][0] + ob10);
    bf16x8 bcE2 = LD8(&smem[0][1][0] + ob01);
    bf16x8 bcE3 = LD8(&smem[0][1][0] + ob11);
    bf16x8 acE  = LD8(&smem[0][0][0] + oa00);
    bf16x8 bcO0 = bcE0, bcO1 = bcE1, bcO2 = bcE2, bcO3 = bcE3, acO = acE; // defined init

    // ---- main loop: 2-tile unroll for register double-buffer parity
    for (int t = 0; t < 124; t += 2) {
        TILE32(t,     bcE0,bcE1,bcE2,bcE3, bcO0,bcO1,bcO2,bcO3, acE, acO, 1, "s_waitcnt vmcnt(8)", 1);
        TILE32(t + 1, bcO0,bcO1,bcO2,bcO3, bcE0,bcE1,bcE2,bcE3, acO, acE, 1, "s_waitcnt vmcnt(8)", 1);
    }
    TILE32(124, bcE0,bcE1,bcE2,bcE3, bcO0,bcO1,bcO2,bcO3, acE, acO, 1, "s_waitcnt vmcnt(8)", 1);
    TILE32(125, bcO0,bcO1,bcO2,bcO3, bcE0,bcE1,bcE2,bcE3, acO, acE, 0, "s_waitcnt vmcnt(4)", 1);
    TILE32(126, bcE0,bcE1,bcE2,bcE3, bcO0,bcO1,bcO2,bcO3, acE, acO, 0, "s_waitcnt vmcnt(0)", 1);
    TILE32(127, bcO0,bcO1,bcO2,bcO3, bcE0,bcE1,bcE2,bcE3, acO, acE, 0, "s_nop 0",            0);

    // ---- epilogue: 32x32 C/D layout: col = lane&31, row = (r&3)+8*(r>>2)+4*(lane>>5)
    const int col0 = bcol + wn * 64 + (lane & 31);
    const int row0 = brow + wm * 128 + 4 * (lane >> 5);
    const float bv0 = bias[col0];
    const float bv1 = bias[col0 + 32];

#pragma unroll
    for (int i = 0; i < 4; i++) {
#pragma unroll
        for (int j = 0; j < 2; j++) {
            const float bv = j ? bv1 : bv0;
            const int colj = col0 + j * 32;
#pragma unroll
            for (int r = 0; r < 16; r++) {
                const size_t row = (size_t)(row0 + i * 32 + (r & 3) + 8 * (r >> 2));
                C[row * N_DIM + colj] = acc[i][j][r] + bv;
            }
        }
    }
}

// ---------------- safety-net fallback (no workspace): plain fp32 dot ----------------
__global__ void gemm_fallback_f32(const float* __restrict__ A, const float* __restrict__ B,
                                  const float* __restrict__ bias, float* __restrict__ C) {
    int n = blockIdx.x * 16 + threadIdx.x;
    int m = blockIdx.y * 16 + threadIdx.y;
    if (m >= M_DIM || n >= N_DIM) return;
    const float4* a = reinterpret_cast<const float4*>(A + (size_t)m * K_DIM);
    const float4* b = reinterpret_cast<const float4*>(B + (size_t)n * K_DIM);
    float s = 0.f;
    for (int k = 0; k < K_DIM / 4; k++) {
        float4 x = a[k], y = b[k];
        s += x.x * y.x + x.y * y.y + x.z * y.z + x.w * y.w;
    }
    C[(size_t)m * N_DIM + n] = s + bias[n];
}

extern "C" void kernel_launch(void* const* d_in, const int* in_sizes, int n_in,
                              void* d_out, int out_size, void* d_ws, size_t ws_size,
                              hipStream_t stream) {
    const float* x    = (const float*)d_in[0];   // [M][K] fp32
    const float* w    = (const float*)d_in[1];   // [N][K] fp32 (B^T layout)
    const float* bias = (const float*)d_in[2];   // [N] fp32
    float* out = (float*)d_out;

    const size_t xb = (size_t)M_DIM * K_DIM * sizeof(bf16_t);   // 64 MB
    const size_t wb = (size_t)N_DIM * K_DIM * sizeof(bf16_t);   // 32 MB

    if (ws_size >= xb + wb) {
        bf16_t* xbf = (bf16_t*)d_ws;
        bf16_t* wbf = (bf16_t*)((char*)d_ws + xb);

        cvt_f32_to_bf16<<<2048, 256, 0, stream>>>(x, xbf, (M_DIM * K_DIM) / 8);
        cvt_f32_to_bf16<<<1024, 256, 0, stream>>>(w, wbf, (N_DIM * K_DIM) / 8);

        const int grid = (M_DIM / BM) * (N_DIM / BN);   // 32 * 16 = 512
        gemm_bf16_32x32<<<grid, 512, 0, stream>>>(xbf, wbf, bias, out);
    } else {
        dim3 block(16, 16);
        dim3 grid(N_DIM / 16, M_DIM / 16);
        gemm_fallback_f32<<<grid, block, 0, stream>>>(x, w, bias, out);
    }
}

// Round 5
// 287.322 us; speedup vs baseline: 1.0627x; 1.0627x over previous
//
#include <hip/hip_runtime.h>
#include <hip/hip_bf16.h>
#include <stdint.h>

#define M_DIM 8192
#define N_DIM 4096   // OUT_F
#define K_DIM 4096   // IN_F

#define BM 256
#define BN 256
#define BK 32
#define NT (K_DIM / BK)   // 128 K-tiles
#define NBUF 4

typedef __bf16 bf16_t;
typedef __attribute__((ext_vector_type(8))) __bf16 bf16x8;
typedef __attribute__((ext_vector_type(4))) float f32x4;

// ---------------- fp32 -> bf16 convert (vectorized, grid-stride) ----------------
__global__ void cvt_f32_to_bf16(const float* __restrict__ in, bf16_t* __restrict__ out, int n8) {
    int stride = gridDim.x * blockDim.x;
    for (int i = blockIdx.x * blockDim.x + threadIdx.x; i < n8; i += stride) {
        const float4* p = reinterpret_cast<const float4*>(in) + 2 * (size_t)i;
        float4 v0 = p[0];
        float4 v1 = p[1];
        bf16x8 o;
        o[0] = (bf16_t)v0.x; o[1] = (bf16_t)v0.y; o[2] = (bf16_t)v0.z; o[3] = (bf16_t)v0.w;
        o[4] = (bf16_t)v1.x; o[5] = (bf16_t)v1.y; o[6] = (bf16_t)v1.z; o[7] = (bf16_t)v1.w;
        *(reinterpret_cast<bf16x8*>(out) + (size_t)i) = o;
    }
}

// ---------------- 256x256 bf16 GEMM, 16x16x32 MFMA, full-cluster read-ahead ----------------
// A: [M][K] bf16 row-major; B: [N][K] bf16 row-major (weight = B^T layout);
// C = A*B^T + bias, fp32 out.
//
// 4-deep LDS K-tile ring (BK=32). Per tile:
//   [stage A(T+3)] [read a4-a7 (cluster-2 A) from buf T] [stage B(T+3)]
//   [cluster 1: 16 MFMA on CARRIED operands (read last tile)]
//   vmcnt(8) ; MID barrier  -> publishes buf[T+1]
//   [read-ahead: next tile's cluster-1 operands aN0-3,bN0-3 from buf T+1]
//   [cluster 2: 16 MFMA on a4-a7 x carried B]
//   END barrier  -> WAR fence for STAGE(T+4)'s DMA overwrite of buf[(T)&3... (T-1)&3]
// Every MFMA's operands are issued >= 1 cluster (~600 cyc) before use -> no
// lgkmcnt stalls; per-CU LDS (96 x b128 ~ 1152 cyc) hides under MFMA (1242 cyc).
// vmcnt audit: at MID(T) outstanding = tiles T+1,T+2,T+3 (4 loads each) = 12;
// vmcnt(8) lands exactly tile T+1. Epilogue drains 8 -> 4 -> 0.

#define MF(a, b, c) __builtin_amdgcn_mfma_f32_16x16x32_bf16((a), (b), (c), 0, 0, 0)
#define LD8(p) (*reinterpret_cast<const bf16x8*>(p))

#define STAGE_A(T) {                                                                  \
    const int sb_ = (T) & 3; const size_t kof_ = (size_t)(T) * BK;                    \
    __builtin_amdgcn_global_load_lds(                                                 \
        (const __attribute__((address_space(1))) void*)(gA0 + kof_),                  \
        (__attribute__((address_space(3))) void*)(&smem[sb_][0][dst0]), 16, 0, 0);    \
    __builtin_amdgcn_global_load_lds(                                                 \
        (const __attribute__((address_space(1))) void*)(gA1 + kof_),                  \
        (__attribute__((address_space(3))) void*)(&smem[sb_][0][dst1]), 16, 0, 0);    \
}

#define STAGE_B(T) {                                                                  \
    const int sb_ = (T) & 3; const size_t kof_ = (size_t)(T) * BK;                    \
    __builtin_amdgcn_global_load_lds(                                                 \
        (const __attribute__((address_space(1))) void*)(gB0 + kof_),                  \
        (__attribute__((address_space(3))) void*)(&smem[sb_][1][dst0]), 16, 0, 0);    \
    __builtin_amdgcn_global_load_lds(                                                 \
        (const __attribute__((address_space(1))) void*)(gB1 + kof_),                  \
        (__attribute__((address_space(3))) void*)(&smem[sb_][1][dst1]), 16, 0, 0);    \
}

#define TILE(T, AC0,AC1,AC2,AC3, BC0,BC1,BC2,BC3,                                     \
             AN0,AN1,AN2,AN3, BN0,BN1,BN2,BN3, STG, VMSTR, RA)                        \
do {                                                                                  \
    bf16_t* Al_ = &smem[(T) & 3][0][0];                                               \
    bf16_t* An_ = &smem[((T) + 1) & 3][0][0];                                         \
    bf16_t* Bn_ = &smem[((T) + 1) & 3][1][0];                                         \
    if (STG) STAGE_A((T) + 3);                                                        \
    /* cluster-2 A frags: first use ~1 cluster later */                               \
    bf16x8 x4_ = LD8(Al_ + oa4);                                                      \
    bf16x8 x5_ = LD8(Al_ + oa5);                                                      \
    bf16x8 x6_ = LD8(Al_ + oa6);                                                      \
    bf16x8 x7_ = LD8(Al_ + oa7);                                                      \
    if (STG) STAGE_B((T) + 3);                                                        \
    /* cluster 1: operands all carried (read last tile) -> no lgkm stall */           \
    __builtin_amdgcn_s_setprio(1);                                                    \
    acc[0][0]=MF(AC0,BC0,acc[0][0]); acc[0][1]=MF(AC0,BC1,acc[0][1]);                 \
    acc[0][2]=MF(AC0,BC2,acc[0][2]); acc[0][3]=MF(AC0,BC3,acc[0][3]);                 \
    acc[1][0]=MF(AC1,BC0,acc[1][0]); acc[1][1]=MF(AC1,BC1,acc[1][1]);                 \
    acc[1][2]=MF(AC1,BC2,acc[1][2]); acc[1][3]=MF(AC1,BC3,acc[1][3]);                 \
    acc[2][0]=MF(AC2,BC0,acc[2][0]); acc[2][1]=MF(AC2,BC1,acc[2][1]);                 \
    acc[2][2]=MF(AC2,BC2,acc[2][2]); acc[2][3]=MF(AC2,BC3,acc[2][3]);                 \
    acc[3][0]=MF(AC3,BC0,acc[3][0]); acc[3][1]=MF(AC3,BC1,acc[3][1]);                 \
    acc[3][2]=MF(AC3,BC2,acc[3][2]); acc[3][3]=MF(AC3,BC3,acc[3][3]);                 \
    __builtin_amdgcn_s_setprio(0);                                                    \
    asm volatile(VMSTR ::: "memory");                                                 \
    __builtin_amdgcn_s_barrier();   /* MID: buf[T+1] staged data now visible */       \
    if (RA) {                                                                         \
        AN0 = LD8(An_ + oa0); AN1 = LD8(An_ + oa1);                                   \
        AN2 = LD8(An_ + oa2); AN3 = LD8(An_ + oa3);                                   \
        BN0 = LD8(Bn_ + ob0); BN1 = LD8(Bn_ + ob1);                                   \
        BN2 = LD8(Bn_ + ob2); BN3 = LD8(Bn_ + ob3);                                   \
    }                                                                                 \
    /* cluster 2: x4-x7 were read ~1 cluster ago */                                   \
    __builtin_amdgcn_s_setprio(1);                                                    \
    acc[4][0]=MF(x4_,BC0,acc[4][0]); acc[4][1]=MF(x4_,BC1,acc[4][1]);                 \
    acc[4][2]=MF(x4_,BC2,acc[4][2]); acc[4][3]=MF(x4_,BC3,acc[4][3]);                 \
    acc[5][0]=MF(x5_,BC0,acc[5][0]); acc[5][1]=MF(x5_,BC1,acc[5][1]);                 \
    acc[5][2]=MF(x5_,BC2,acc[5][2]); acc[5][3]=MF(x5_,BC3,acc[5][3]);                 \
    acc[6][0]=MF(x6_,BC0,acc[6][0]); acc[6][1]=MF(x6_,BC1,acc[6][1]);                 \
    acc[6][2]=MF(x6_,BC2,acc[6][2]); acc[6][3]=MF(x6_,BC3,acc[6][3]);                 \
    acc[7][0]=MF(x7_,BC0,acc[7][0]); acc[7][1]=MF(x7_,BC1,acc[7][1]);                 \
    acc[7][2]=MF(x7_,BC2,acc[7][2]); acc[7][3]=MF(x7_,BC3,acc[7][3]);                 \
    __builtin_amdgcn_s_setprio(0);                                                    \
    __builtin_amdgcn_s_barrier();   /* END: WAR fence for next STAGE */               \
} while (0)

__global__ __launch_bounds__(512, 2) void gemm_bf16_ra(
        const bf16_t* __restrict__ A, const bf16_t* __restrict__ B,
        const float* __restrict__ bias, float* __restrict__ C) {

    __shared__ __align__(16) bf16_t smem[NBUF][2][BM * BK];   // 4 x (A,B) x 16KB = 128 KiB

    const int tid  = threadIdx.x;
    const int lane = tid & 63;
    const int wave = tid >> 6;        // 0..7
    const int wm   = wave >> 2;       // 0..1 : M half (128 rows)
    const int wn   = wave & 3;        // 0..3 : N quarter (64 cols)

    // XCD-aware swizzle (nwg = 512, divisible by 8 -> bijective)
    const int nwg = gridDim.x;
    const int cpx = nwg >> 3;
    const int swz = (blockIdx.x & 7) * cpx + (blockIdx.x >> 3);
    const int ntn = N_DIM / BN;       // 16
    const int brow = (swz / ntn) * BM;
    const int bcol = (swz % ntn) * BN;

    // ---- staging geometry (r2-proven): tile = 256 rows x 32 bf16 = 16KB =
    // 1024 x 16B chunks; slot s holds (row = s>>2, chunk = (s&3)^((s>>3)&3)).
    const int slot0 = wave * 128 + lane;
    const int slot1 = slot0 + 64;
    const int r0 = slot0 >> 2, c0 = ((slot0 & 3) ^ ((slot0 >> 3) & 3)) << 3;
    const int r1 = slot1 >> 2, c1 = ((slot1 & 3) ^ ((slot1 >> 3) & 3)) << 3;
    const bf16_t* gA0 = A + (size_t)(brow + r0) * K_DIM + c0;
    const bf16_t* gA1 = A + (size_t)(brow + r1) * K_DIM + c1;
    const bf16_t* gB0 = B + (size_t)(bcol + r0) * K_DIM + c0;
    const bf16_t* gB1 = B + (size_t)(bcol + r1) * K_DIM + c1;
    const int dst0 = wave * 1024;     // elem offset (slot * 8)
    const int dst1 = dst0 + 512;

    // ---- ds_read fragment offsets (r2-proven, measured 0 bank conflicts)
    const int fr = lane & 15;
    const int cc = lane >> 4;         // k-chunk 0..3 (k = cc*8)
#define AOFF(p, mi) ({ int row_ = wm*128 + (p)*64 + (mi)*16 + fr; \
                       row_*32 + ((cc ^ ((row_ >> 1) & 3)) << 3); })
#define BOFF(ni)    ({ int row_ = wn*64 + (ni)*16 + fr; \
                       row_*32 + ((cc ^ ((row_ >> 1) & 3)) << 3); })
    const int oa0 = AOFF(0,0), oa1 = AOFF(0,1), oa2 = AOFF(0,2), oa3 = AOFF(0,3);
    const int oa4 = AOFF(1,0), oa5 = AOFF(1,1), oa6 = AOFF(1,2), oa7 = AOFF(1,3);
    const int ob0 = BOFF(0), ob1 = BOFF(1), ob2 = BOFF(2), ob3 = BOFF(3);

    f32x4 acc[8][4];
#pragma unroll
    for (int i = 0; i < 8; i++)
#pragma unroll
        for (int j = 0; j < 4; j++)
            acc[i][j] = (f32x4){0.f, 0.f, 0.f, 0.f};

    // ---- prologue: stage tiles 0,1,2; land tile 0 (12 outstanding -> 8)
    STAGE_A(0) STAGE_B(0)
    STAGE_A(1) STAGE_B(1)
    STAGE_A(2) STAGE_B(2)
    asm volatile("s_waitcnt vmcnt(8)" ::: "memory");
    __builtin_amdgcn_s_barrier();

    // pre-read tile 0's cluster-1 operands into the E set
    bf16x8 aE0 = LD8(&smem[0][0][0] + oa0);
    bf16x8 aE1 = LD8(&smem[0][0][0] + oa1);
    bf16x8 aE2 = LD8(&smem[0][0][0] + oa2);
    bf16x8 aE3 = LD8(&smem[0][0][0] + oa3);
    bf16x8 bE0 = LD8(&smem[0][1][0] + ob0);
    bf16x8 bE1 = LD8(&smem[0][1][0] + ob1);
    bf16x8 bE2 = LD8(&smem[0][1][0] + ob2);
    bf16x8 bE3 = LD8(&smem[0][1][0] + ob3);
    bf16x8 aO0 = aE0, aO1 = aE1, aO2 = aE2, aO3 = aE3;   // defined init
    bf16x8 bO0 = bE0, bO1 = bE1, bO2 = bE2, bO3 = bE3;

    // ---- main loop: 2-tile unroll for E/O register parity
    for (int t = 0; t < 124; t += 2) {
        TILE(t,   aE0,aE1,aE2,aE3, bE0,bE1,bE2,bE3,
                  aO0,aO1,aO2,aO3, bO0,bO1,bO2,bO3, 1, "s_waitcnt vmcnt(8)", 1);
        TILE(t+1, aO0,aO1,aO2,aO3, bO0,bO1,bO2,bO3,
                  aE0,aE1,aE2,aE3, bE0,bE1,bE2,bE3, 1, "s_waitcnt vmcnt(8)", 1);
    }
    TILE(124, aE0,aE1,aE2,aE3, bE0,bE1,bE2,bE3,
              aO0,aO1,aO2,aO3, bO0,bO1,bO2,bO3, 1, "s_waitcnt vmcnt(8)", 1);
    TILE(125, aO0,aO1,aO2,aO3, bO0,bO1,bO2,bO3,
              aE0,aE1,aE2,aE3, bE0,bE1,bE2,bE3, 0, "s_waitcnt vmcnt(4)", 1);
    TILE(126, aE0,aE1,aE2,aE3, bE0,bE1,bE2,bE3,
              aO0,aO1,aO2,aO3, bO0,bO1,bO2,bO3, 0, "s_waitcnt vmcnt(0)", 1);
    TILE(127, aO0,aO1,aO2,aO3, bO0,bO1,bO2,bO3,
              aE0,aE1,aE2,aE3, bE0,bE1,bE2,bE3, 0, "s_nop 0",            0);

    // ---- epilogue: C/D layout col = lane&15, row = (lane>>4)*4 + r
    const int cc0 = bcol + wn * 64 + (lane & 15);
    const int rr0 = brow + wm * 128 + (lane >> 4) * 4;

    float bv[4];
#pragma unroll
    for (int ni = 0; ni < 4; ni++) bv[ni] = bias[cc0 + ni * 16];

#pragma unroll
    for (int p = 0; p < 2; p++) {
#pragma unroll
        for (int i = 0; i < 4; i++) {
#pragma unroll
            for (int r = 0; r < 4; r++) {
                const size_t row = (size_t)(rr0 + p * 64 + i * 16 + r);
#pragma unroll
                for (int ni = 0; ni < 4; ni++) {
                    C[row * N_DIM + cc0 + ni * 16] = acc[p * 4 + i][ni][r] + bv[ni];
                }
            }
        }
    }
}

// ---------------- safety-net fallback (no workspace): plain fp32 dot ----------------
__global__ void gemm_fallback_f32(const float* __restrict__ A, const float* __restrict__ B,
                                  const float* __restrict__ bias, float* __restrict__ C) {
    int n = blockIdx.x * 16 + threadIdx.x;
    int m = blockIdx.y * 16 + threadIdx.y;
    if (m >= M_DIM || n >= N_DIM) return;
    const float4* a = reinterpret_cast<const float4*>(A + (size_t)m * K_DIM);
    const float4* b = reinterpret_cast<const float4*>(B + (size_t)n * K_DIM);
    float s = 0.f;
    for (int k = 0; k < K_DIM / 4; k++) {
        float4 x = a[k], y = b[k];
        s += x.x * y.x + x.y * y.y + x.z * y.z + x.w * y.w;
    }
    C[(size_t)m * N_DIM + n] = s + bias[n];
}

extern "C" void kernel_launch(void* const* d_in, const int* in_sizes, int n_in,
                              void* d_out, int out_size, void* d_ws, size_t ws_size,
                              hipStream_t stream) {
    const float* x    = (const float*)d_in[0];   // [M][K] fp32
    const float* w    = (const float*)d_in[1];   // [N][K] fp32 (B^T layout)
    const float* bias = (const float*)d_in[2];   // [N] fp32
    float* out = (float*)d_out;

    const size_t xb = (size_t)M_DIM * K_DIM * sizeof(bf16_t);   // 64 MB
    const size_t wb = (size_t)N_DIM * K_DIM * sizeof(bf16_t);   // 32 MB

    if (ws_size >= xb + wb) {
        bf16_t* xbf = (bf16_t*)d_ws;
        bf16_t* wbf = (bf16_t*)((char*)d_ws + xb);

        cvt_f32_to_bf16<<<2048, 256, 0, stream>>>(x, xbf, (M_DIM * K_DIM) / 8);
        cvt_f32_to_bf16<<<1024, 256, 0, stream>>>(w, wbf, (N_DIM * K_DIM) / 8);

        const int grid = (M_DIM / BM) * (N_DIM / BN);   // 32 * 16 = 512
        gemm_bf16_ra<<<grid, 512, 0, stream>>>(xbf, wbf, bias, out);
    } else {
        dim3 block(16, 16);
        dim3 grid(N_DIM / 16, M_DIM / 16);
        gemm_fallback_f32<<<grid, block, 0, stream>>>(x, w, bias, out);
    }
}